// Round 11
// baseline (209.260 us; speedup 1.0000x reference)
//
#include <hip/hip_runtime.h>
#include <hip/hip_bf16.h>
#include <stdint.h>

// CustomAttention: B=2, S=2048, E=1024, H=16, D=64, causal. I/O f32.
// cvt (f32->bf16 precast), qkv_gemm (bf16, BK=64 via two [128][32] panels,
// Q pre-scaled by SCALE*log2e, V written TRANSPOSED [b,h,d,s]), flash-attn
// (S^T formulation, balanced per-CU quartet; V staged via global_load_lds
// into XOR-swizzled double buffer), out_gemm (64x64 tiles).
//
// Failed-variant ledger (do not retry):
//  - attn KVBLK=128 reg-prefetch: spills (WRITE 8->78MB, 46->69us).
//  - attn 1-barrier LDS dbuf (reg->ds_write): lgkmcnt in-order retire puts
//    the write phase on the read critical path (46.5->52us).
//  - attn setprio on MFMA clusters: 4-wave lockstep = m190 regime, +2.6us.
//  - qkv XCD-rect swizzle: post-timing nondeterministic divergence. Reverted.
//  - attn 128-q/8-wave block: halves independent barrier groups/CU, +5us.
//  - __launch_bounds__(256,8): min-waves arg CAPS total regs (gfx950
//    unified file) at 64 -> VGPR 32 + 167MB spill, attn 128us.
//  - SQ_LDS_BANK_CONFLICT reads a constant 2162688 across ALL structures:
//    artifact; do not chase.

typedef __hip_bfloat16 bf16;
typedef short bf16x8 __attribute__((ext_vector_type(8)));
typedef short bf16x4 __attribute__((ext_vector_type(4)));
typedef float f32x4 __attribute__((ext_vector_type(4)));

__device__ __forceinline__ f32x4 mfma16(bf16x8 a, bf16x8 b, f32x4 c) {
  return __builtin_amdgcn_mfma_f32_16x16x32_bf16(a, b, c, 0, 0, 0);
}

// 16x16x16 bf16 MFMA (K=16): A[m=ln][k=4g+i], B[k=4g+i][n=ln], C/D standard.
__device__ __forceinline__ f32x4 mfma_k16(bf16x4 a, bf16x4 b, f32x4 c) {
#if __has_builtin(__builtin_amdgcn_mfma_f32_16x16x16bf16_1k)
  return __builtin_amdgcn_mfma_f32_16x16x16bf16_1k(a, b, c, 0, 0, 0);
#else
  f32x4 d;
  asm volatile("v_mfma_f32_16x16x16_bf16 %0, %1, %2, %3\n\ts_nop 7\n\ts_nop 7"
               : "=v"(d)
               : "v"(a), "v"(b), "v"(c));
  return d;
#endif
}

__device__ __forceinline__ void async16(const void* g, void* l) {
  __builtin_amdgcn_global_load_lds((const __attribute__((address_space(1))) void*)g,
                                   (__attribute__((address_space(3))) void*)l, 16, 0, 0);
}

// ---- precast: hs (4M) + Wq,Wk,Wv,Wo (1M each) f32 -> one 8M bf16 array ----
__global__ __launch_bounds__(256) void cvt_kernel(
    const float* __restrict__ hs, const float* __restrict__ Wq,
    const float* __restrict__ Wk, const float* __restrict__ Wv,
    const float* __restrict__ Wo, bf16* __restrict__ dst) {
  const size_t e = ((size_t)blockIdx.x * 256 + threadIdx.x) * 8;
  const float* src;
  size_t off;
  if (e < 4194304) {
    src = hs; off = e;
  } else {
    const size_t w = e - 4194304;
    const int wi = (int)(w >> 20);
    src = (wi == 0) ? Wq : (wi == 1) ? Wk : (wi == 2) ? Wv : Wo;
    off = w & 1048575;
  }
  const float4 a = *(const float4*)(src + off);
  const float4 b = *(const float4*)(src + off + 4);
  union { bf16 h[8]; uint4 u; } p;
  p.h[0] = __float2bfloat16(a.x); p.h[1] = __float2bfloat16(a.y);
  p.h[2] = __float2bfloat16(a.z); p.h[3] = __float2bfloat16(a.w);
  p.h[4] = __float2bfloat16(b.x); p.h[5] = __float2bfloat16(b.y);
  p.h[6] = __float2bfloat16(b.z); p.h[7] = __float2bfloat16(b.w);
  *(uint4*)(dst + e) = p.u;
}

// ---- fused QKV GEMM (all bf16). M=4096, N=3072, K=1024. BK=64 as two
// [128][32] panels. V (which==2) is stored TRANSPOSED [b,h,d,s]: the C-frag
// holds 4 consecutive s per lane (rows 4g+r), so V^T needs one packed 8B
// store per frag (16 total) instead of 64 scalar stores. LDS 32KB/block. ----
__global__ __launch_bounds__(256, 3) void qkv_gemm(
    const bf16* __restrict__ X, const bf16* __restrict__ Wb,
    const float* __restrict__ bq, const float* __restrict__ bk,
    const float* __restrict__ bv, bf16* __restrict__ out) {
  constexpr int Kd = 1024;
  __shared__ bf16 sA[2][128 * 32];
  __shared__ bf16 sB[2][128 * 32];
  const int tid = threadIdx.x;
  const int wave = tid >> 6, lane = tid & 63;
  const int g = lane >> 4, ln = lane & 15;
  const int tM = blockIdx.y * 128, tN = blockIdx.x * 128;
  const int which = tN >> 10;  // 0=Q 1=K 2=V
  const bf16* W = Wb + (size_t)which * 1048576;
  const float* bias = (which == 0) ? bq : (which == 1) ? bk : bv;
  const int tNl = tN & 1023;
  const float oscale = (which == 0) ? 0.18033688011112042f : 1.0f;  // 0.125*log2e
  const int wrow = (wave >> 1) * 64, wcol = (wave & 1) * 64;
  const f32x4 fz = {0.f, 0.f, 0.f, 0.f};

  f32x4 acc[4][4];
#pragma unroll
  for (int i = 0; i < 4; ++i)
#pragma unroll
    for (int j = 0; j < 4; ++j) acc[i][j] = fz;

  // staging decomposition: dest chunk d (16B) -> panel=d>>9, row=(d>>2)&127,
  // cc=d&3; global col = panel*32 + cc*8. Per-wave dests stay linear.
  int srow[4], scol[4];
#pragma unroll
  for (int t = 0; t < 4; ++t) {
    const int d = tid + t * 256;
    srow[t] = (d >> 2) & 127;
    scol[t] = ((d >> 9) << 5) + ((d & 3) << 3);
  }

  for (int k0 = 0; k0 < Kd; k0 += 64) {
    __syncthreads();
#pragma unroll
    for (int t = 0; t < 4; ++t) {
      const int d = tid + t * 256;
      async16(X + (size_t)(tM + srow[t]) * Kd + k0 + scol[t], &sA[0][0] + d * 8);
      async16(W + (size_t)(tNl + srow[t]) * Kd + k0 + scol[t], &sB[0][0] + d * 8);
    }
    __syncthreads();
#pragma unroll
    for (int kk = 0; kk < 2; ++kk) {
      bf16x8 aF[4], bF[4];
#pragma unroll
      for (int i = 0; i < 4; ++i)
        aF[i] = *(const bf16x8*)(&sA[kk][0] + (wrow + i * 16 + ln) * 32 + g * 8);
#pragma unroll
      for (int j = 0; j < 4; ++j)
        bF[j] = *(const bf16x8*)(&sB[kk][0] + (wcol + j * 16 + ln) * 32 + g * 8);
#pragma unroll
      for (int i = 0; i < 4; ++i)
#pragma unroll
        for (int j = 0; j < 4; ++j) acc[i][j] = mfma16(aF[i], bF[j], acc[i][j]);
    }
  }

  bf16* outw = out + (size_t)which * 4194304;
  if (which == 2) {
    // V^T epilogue: [b,h,d,s]; lane's 4 acc values are s-consecutive.
#pragma unroll
    for (int j = 0; j < 4; ++j) {
      const int nl = tNl + wcol + j * 16 + ln;
      const float bvf = bias[nl];
      const int h = nl >> 6, d = nl & 63;
#pragma unroll
      for (int i = 0; i < 4; ++i) {
        const int m0 = tM + wrow + i * 16 + g * 4;
        const int b = m0 >> 11, s0 = m0 & 2047;
        union { bf16 hh[4]; bf16x4 v; } pk;
#pragma unroll
        for (int r = 0; r < 4; ++r) pk.hh[r] = __float2bfloat16(acc[i][j][r] + bvf);
        *(bf16x4*)(outw + (((size_t)(b * 16 + h) * 64 + d) << 11) + s0) = pk.v;
      }
    }
  } else {
#pragma unroll
    for (int j = 0; j < 4; ++j) {
      const int nl = tNl + wcol + j * 16 + ln;
      const float bvf = bias[nl];
      const int h = nl >> 6, d = nl & 63;
#pragma unroll
      for (int i = 0; i < 4; ++i) {
#pragma unroll
        for (int r = 0; r < 4; ++r) {
          const int m = tM + wrow + i * 16 + g * 4 + r;
          const int b = m >> 11, s = m & 2047;
          const float v = (acc[i][j][r] + bvf) * oscale;
          outw[(((size_t)(b * 16 + h) * 2048 + s) << 6) + d] = __float2bfloat16(v);
        }
      }
    }
  }
}

// ---- out projection (bf16 x bf16 -> f32). 64x64 tiles, grid (16,64) ----
__global__ __launch_bounds__(256, 4) void out_gemm(
    const bf16* __restrict__ X, const bf16* __restrict__ W,
    const float* __restrict__ bias, float* __restrict__ out) {
  constexpr int Kd = 1024;
  __shared__ bf16 sA[64 * 32];
  __shared__ bf16 sB[64 * 32];
  const int tid = threadIdx.x;
  const int wave = tid >> 6, lane = tid & 63;
  const int g = lane >> 4, ln = lane & 15;
  const int tM = blockIdx.y * 64, tN = blockIdx.x * 64;
  const f32x4 fz = {0.f, 0.f, 0.f, 0.f};

  f32x4 acc[4];
#pragma unroll
  for (int j = 0; j < 4; ++j) acc[j] = fz;

  const int srow = tid >> 2, scol = (tid & 3) << 3;
  for (int k0 = 0; k0 < Kd; k0 += 32) {
    __syncthreads();
    async16(X + (size_t)(tM + srow) * Kd + k0 + scol, sA + tid * 8);
    async16(W + (size_t)(tN + srow) * Kd + k0 + scol, sB + tid * 8);
    __syncthreads();
    const bf16x8 aF = *(const bf16x8*)(sA + (wave * 16 + ln) * 32 + g * 8);
    bf16x8 bF[4];
#pragma unroll
    for (int j = 0; j < 4; ++j)
      bF[j] = *(const bf16x8*)(sB + (j * 16 + ln) * 32 + g * 8);
#pragma unroll
    for (int j = 0; j < 4; ++j) acc[j] = mfma16(aF, bF[j], acc[j]);
  }

#pragma unroll
  for (int j = 0; j < 4; ++j) {
    const int n = tN + j * 16 + ln;
    const float bvf = bias[n];
#pragma unroll
    for (int r = 0; r < 4; ++r) {
      const int m = tM + wave * 16 + g * 4 + r;
      out[(size_t)m * 1024 + n] = acc[j][r] + bvf;
    }
  }
}

// ---- flash attention, causal, S^T formulation, fixed-max softmax ----
// Balanced per-CU quartet mapping (r10, verified −6.5%). V is consumed from
// the TRANSPOSED [b,h,d,s] buffer: staged by 2 global_load_lds/thread into
// sVt[2][64*64] (double-buffered; issued after barrier B, in flight across
// the whole compute phase, drained at next barrier A — no barrier crossed
// while in flight). Linear LDS dest forces an XOR swizzle (both-sides,
// rule #21): 16B-chunk index cc ^= (d&3)<<1 on the global source; the PV
// read applies the same XOR -> b64 bank floor. K path unchanged (reg-staged,
// 72-pad). Row-sum on the MFMA pipe (ones-B-frag).
// LDS: sK[64][72] (9.2KB) + sVt 16KB = 25.6KB -> 4 blocks/CU.
__global__ __launch_bounds__(256, 4) void attn_kernel(
    const bf16* __restrict__ Q, const bf16* __restrict__ K,
    const bf16* __restrict__ V, bf16* __restrict__ O) {
  constexpr int S = 2048, D = 64;
  __shared__ bf16 sK[64 * 72];
  __shared__ bf16 sVt[2][64 * 64];

  const int tid = threadIdx.x;
  const int w = tid >> 6, lane = tid & 63;
  const int g = lane >> 4, ln = lane & 15;
  // work remap: (px,py) -> (bh, qt), bijective (balanced quartet, r10).
  const int px = blockIdx.x, py = blockIdx.y;
  const int bh = (px & 7) * 4 + (py & 3);             // XCD-pinned head
  const int s = py >> 3;                              // CU-slot quadrant
  const int q0 = (px >> 3) + 4 * ((py >> 2) & 1);     // [0,8)
  const int qt = (s == 0) ? 31 - q0
               : (s == 1) ? 16 + q0
               : (s == 2) ? 15 - q0
                          : q0;
  const int b = bh >> 4, h = bh & 15;
  const f32x4 fz = {0.f, 0.f, 0.f, 0.f};

  const bf16* Qb = Q + (size_t)bh * S * D;
  const bf16* Kb = K + (size_t)bh * S * D;
  const bf16* Vt = V + (size_t)bh * 64 * 2048;  // [d][s]

  // K staging coords (2 x b128 per thread)
  const int kr0 = tid >> 3, kc0 = (tid & 7) << 3;
  // V staging via async16: chunks p = tid, tid+256 -> row d=p>>3, chunk cc=p&7;
  // global source pre-swizzled: cc ^= (d&3)<<1 (read side applies same XOR).
  int voff[2];
#pragma unroll
  for (int t = 0; t < 2; ++t) {
    const int p = tid + t * 256;
    const int d = p >> 3, cc = p & 7;
    voff[t] = d * 2048 + ((cc ^ ((d & 3) << 1)) << 3);
  }

  // Q B-frags (B[k=d][n=q]: n=ln, k=g*8+j); Q pre-scaled by SCALE*log2e
  bf16x8 qf[2];
#pragma unroll
  for (int kc = 0; kc < 2; ++kc)
    qf[kc] = *(const bf16x8*)(Qb + (size_t)(qt * 64 + w * 16 + ln) * D + kc * 32 + g * 8);

  f32x4 oacc[4];
#pragma unroll
  for (int db = 0; db < 4; ++db) oacc[db] = fz;
  f32x4 lacc = fz;  // row-sum accumulator (MFMA ones trick)
  const short onebf = (short)0x3F80;  // bf16 1.0
  const bf16x4 onesf = {onebf, onebf, onebf, onebf};

  // PV read swizzle terms (lane-constant): chunk (2kb + g>>1) ^ ((ln&3)<<1),
  // sub-chunk (g&1)*4.
  int sx[4];
  {
    const int s8b = g >> 1, xr = (ln & 3) << 1, vlo = (g & 1) << 2;
#pragma unroll
    for (int kb = 0; kb < 4; ++kb) sx[kb] = (((2 * kb + s8b) ^ xr) << 3) + vlo;
  }

  // prologue: K tile 0 -> regs; V tile 0 -> sVt[0] via async16
  uint4 kreg0 = *(const uint4*)(Kb + (size_t)kr0 * D + kc0);
  uint4 kreg1 = *(const uint4*)(Kb + (size_t)(kr0 + 32) * D + kc0);
  async16(Vt + voff[0], &sVt[0][0] + tid * 8);
  async16(Vt + voff[1], &sVt[0][0] + (tid + 256) * 8);

  for (int kt = 0; kt <= qt; ++kt) {
    __syncthreads();  // barrier A: V(kt) drained; prev-iter LDS reads retired
    *(uint4*)(sK + kr0 * 72 + kc0) = kreg0;
    *(uint4*)(sK + (kr0 + 32) * 72 + kc0) = kreg1;
    __syncthreads();  // barrier B: sK visible
    if (kt < qt) {
      const int nb = (kt + 1) << 6;
      bf16* vb = &sVt[(kt + 1) & 1][0];
      async16(Vt + voff[0] + nb, vb + tid * 8);          // in flight across compute
      async16(Vt + voff[1] + nb, vb + (tid + 256) * 8);
      const size_t nr = (size_t)nb;
      kreg0 = *(const uint4*)(Kb + (nr + kr0) * D + kc0);
      kreg1 = *(const uint4*)(Kb + (nr + kr0 + 32) * D + kc0);
    }

    // S^T = K.Q^T : A=K (m=key), B=Q (n=q); 4 key-blocks x 2 k-chunks
    f32x4 sacc[4];
#pragma unroll
    for (int kb = 0; kb < 4; ++kb) sacc[kb] = fz;
#pragma unroll
    for (int kb = 0; kb < 4; ++kb) {
      const bf16x8 k0 = *(const bf16x8*)(sK + (kb * 16 + ln) * 72 + g * 8);
      const bf16x8 k1 = *(const bf16x8*)(sK + (kb * 16 + ln) * 72 + 32 + g * 8);
      sacc[kb] = mfma16(k0, qf[0], sacc[kb]);
      sacc[kb] = mfma16(k1, qf[1], sacc[kb]);
    }

    // softmax (fixed-max, log2 domain) + causal zero + pack PV A-frags;
    // row-sum folded into lacc on the MFMA pipe.
    const bool diag = (kt == qt);
    const int qloc = w * 16 + ln;  // q row within q-tile
    bf16x4 pa[4];
#pragma unroll
    for (int kb = 0; kb < 4; ++kb) {
      union { bf16 hh[4]; bf16x4 v; } pu;
#pragma unroll
      for (int r = 0; r < 4; ++r) {
        float pv = exp2f(sacc[kb][r]);
        if (diag && (kb * 16 + g * 4 + r > qloc)) pv = 0.f;
        pu.hh[r] = __float2bfloat16(pv);
      }
      pa[kb] = pu.v;
      lacc = mfma_k16(pa[kb], onesf, lacc);
    }

    // O += P V : 16x16x16, A=pa (m=q,k=s), B=V^T rows (k=s,n=d), swizzled
    const bf16* sVc = &sVt[kt & 1][0];
#pragma unroll
    for (int db = 0; db < 4; ++db) {
      const int rowb = (db * 16 + ln) * 64;
#pragma unroll
      for (int kb = 0; kb < 4; ++kb) {
        const bf16x4 vf = *(const bf16x4*)(sVc + rowb + sx[kb]);
        oacc[db] = mfma_k16(pa[kb], vf, oacc[db]);
      }
    }
  }

  // lacc[r] = rowsum for q-row g*4+r (same rows as oacc) -> direct reciprocal
  float invl[4];
#pragma unroll
  for (int r = 0; r < 4; ++r) invl[r] = 1.0f / lacc[r];

  // write ctx [B,S,H,D]: rows = q (4g+r), cols = d (db*16+ln)
#pragma unroll
  for (int db = 0; db < 4; ++db)
#pragma unroll
    for (int r = 0; r < 4; ++r) {
      const int row = qt * 64 + w * 16 + g * 4 + r;
      const int col = db * 16 + ln;
      O[(((size_t)(b * 2048 + row) * 16 + h) << 6) + col] =
          __float2bfloat16(oacc[db][r] * invl[r]);
    }
}

extern "C" void kernel_launch(void* const* d_in, const int* in_sizes, int n_in,
                              void* d_out, int out_size, void* d_ws, size_t ws_size,
                              hipStream_t stream) {
  const float* hs = (const float*)d_in[0];
  // d_in[1] = attn_mask (f32): exactly causal -> applied analytically, not read.
  const float* Wq = (const float*)d_in[2];
  const float* bq = (const float*)d_in[3];
  const float* Wk = (const float*)d_in[4];
  const float* bk = (const float*)d_in[5];
  const float* Wv = (const float*)d_in[6];
  const float* bv = (const float*)d_in[7];
  const float* Wo = (const float*)d_in[8];
  const float* bo = (const float*)d_in[9];
  float* out = (float*)d_out;

  char* ws = (char*)d_ws;
  bf16* XW = (bf16*)ws;                  // [0,16MB): Xb 4M + W's 4x1M bf16
  bf16* Xb = XW;
  bf16* W3b = XW + 4194304;              // Wq,Wk,Wv bf16
  bf16* Wob = XW + 7340032;              // Wo bf16
  bf16* Qw = (bf16*)(ws + (16u << 20));  // [B,H,S,D] bf16, 8 MB each
  bf16* Kw = (bf16*)(ws + (24u << 20));
  bf16* Vw = (bf16*)(ws + (32u << 20));  // V^T: [B,H,D,S] bf16
  bf16* Cw = (bf16*)ws;                  // ctx overlays Xb (dead by then)

  const dim3 blk(256);
  cvt_kernel<<<4096, blk, 0, stream>>>(hs, Wq, Wk, Wv, Wo, XW);
  qkv_gemm<<<dim3(24, 32), blk, 0, stream>>>(Xb, W3b, bq, bk, bv, Qw);
  attn_kernel<<<dim3(32, 32), blk, 0, stream>>>(Qw, Kw, Vw, Cw);
  out_gemm<<<dim3(16, 64), blk, 0, stream>>>(Cw, Wob, bo, out);
}

// Round 12
// 203.527 us; speedup vs baseline: 1.0282x; 1.0282x over previous
//
#include <hip/hip_runtime.h>
#include <hip/hip_bf16.h>
#include <stdint.h>

// CustomAttention: B=2, S=2048, E=1024, H=16, D=64, causal. I/O f32.
// cvt (f32->bf16 precast), qkv_gemm (bf16, BK=32 double-buffered
// global_load_lds staging, 1 barrier/iter, Q pre-scaled by SCALE*log2e),
// flash-attn (S^T formulation, balanced per-CU quartet — round-10 verified
// best), out_gemm (64x64 tiles, double-buffered staging).
//
// Failed-variant ledger (do not retry):
//  - attn KVBLK=128 reg-prefetch: spills (WRITE 8->78MB, 46->69us).
//  - attn 1-barrier LDS dbuf via reg->ds_write: lgkmcnt in-order retire puts
//    the write phase on the read critical path (46.5->52us). (global_load_lds
//    dbuf is a DIFFERENT mechanism: vmcnt, not lgkmcnt — used in qkv/out.)
//  - attn setprio on MFMA clusters: 4-wave lockstep = m190 regime, +2.6us.
//  - qkv XCD-rect swizzle: post-timing nondeterministic divergence. Reverted.
//  - attn 128-q/8-wave block: halves independent barrier groups/CU, +5us.
//  - __launch_bounds__(256,8): min-waves arg CAPS total regs (gfx950 unified
//    file) at 64 -> VGPR 32 + 167MB spill, attn 128us.
//  - attn V^T consume + XOR-chunk swizzle: rows stride 128B = one bank
//    period, so bank sees only chunk bits -> unavoidable 4-way conflict on
//    PV b64 reads (SQ_LDS_BANK_CONFLICT 2.16M->15.1M, attn 43.9->57.6us).
//    Frag-major (lane-contiguous) V in LDS is bank-optimal; keep the repack.
//  - SQ_LDS_BANK_CONFLICT==2162688 is the attn structure's REAL constant
//    (it moved 7x when the pattern changed) — a valid regression canary.

typedef __hip_bfloat16 bf16;
typedef short bf16x8 __attribute__((ext_vector_type(8)));
typedef short bf16x4 __attribute__((ext_vector_type(4)));
typedef float f32x4 __attribute__((ext_vector_type(4)));

__device__ __forceinline__ f32x4 mfma16(bf16x8 a, bf16x8 b, f32x4 c) {
  return __builtin_amdgcn_mfma_f32_16x16x32_bf16(a, b, c, 0, 0, 0);
}

// 16x16x16 bf16 MFMA (K=16): A[m=ln][k=4g+i], B[k=4g+i][n=ln], C/D standard.
__device__ __forceinline__ f32x4 mfma_k16(bf16x4 a, bf16x4 b, f32x4 c) {
#if __has_builtin(__builtin_amdgcn_mfma_f32_16x16x16bf16_1k)
  return __builtin_amdgcn_mfma_f32_16x16x16bf16_1k(a, b, c, 0, 0, 0);
#else
  f32x4 d;
  asm volatile("v_mfma_f32_16x16x16_bf16 %0, %1, %2, %3\n\ts_nop 7\n\ts_nop 7"
               : "=v"(d)
               : "v"(a), "v"(b), "v"(c));
  return d;
#endif
}

__device__ __forceinline__ void async16(const void* g, void* l) {
  __builtin_amdgcn_global_load_lds((const __attribute__((address_space(1))) void*)g,
                                   (__attribute__((address_space(3))) void*)l, 16, 0, 0);
}

// ---- precast: hs (4M) + Wq,Wk,Wv,Wo (1M each) f32 -> one 8M bf16 array ----
__global__ __launch_bounds__(256) void cvt_kernel(
    const float* __restrict__ hs, const float* __restrict__ Wq,
    const float* __restrict__ Wk, const float* __restrict__ Wv,
    const float* __restrict__ Wo, bf16* __restrict__ dst) {
  const size_t e = ((size_t)blockIdx.x * 256 + threadIdx.x) * 8;
  const float* src;
  size_t off;
  if (e < 4194304) {
    src = hs; off = e;
  } else {
    const size_t w = e - 4194304;
    const int wi = (int)(w >> 20);
    src = (wi == 0) ? Wq : (wi == 1) ? Wk : (wi == 2) ? Wv : Wo;
    off = w & 1048575;
  }
  const float4 a = *(const float4*)(src + off);
  const float4 b = *(const float4*)(src + off + 4);
  union { bf16 h[8]; uint4 u; } p;
  p.h[0] = __float2bfloat16(a.x); p.h[1] = __float2bfloat16(a.y);
  p.h[2] = __float2bfloat16(a.z); p.h[3] = __float2bfloat16(a.w);
  p.h[4] = __float2bfloat16(b.x); p.h[5] = __float2bfloat16(b.y);
  p.h[6] = __float2bfloat16(b.z); p.h[7] = __float2bfloat16(b.w);
  *(uint4*)(dst + e) = p.u;
}

// ---- fused QKV GEMM (all bf16). M=4096, N=3072, K=1024. BK=32, DOUBLE-
// BUFFERED global_load_lds staging (1 barrier/iter): next tile is issued
// right after the barrier and drains under the compute phase, so the
// barrier's implicit vmcnt(0) no longer exposes full load latency.
// LDS 2x(8+8)KB = 32KB (same as before), 3 blocks/CU. ----
__global__ __launch_bounds__(256, 3) void qkv_gemm(
    const bf16* __restrict__ X, const bf16* __restrict__ Wb,
    const float* __restrict__ bq, const float* __restrict__ bk,
    const float* __restrict__ bv, bf16* __restrict__ out) {
  constexpr int Kd = 1024;
  __shared__ bf16 sA[2][128 * 32];
  __shared__ bf16 sB[2][128 * 32];
  const int tid = threadIdx.x;
  const int wave = tid >> 6, lane = tid & 63;
  const int g = lane >> 4, ln = lane & 15;
  const int tM = blockIdx.y * 128, tN = blockIdx.x * 128;
  const int which = tN >> 10;  // 0=Q 1=K 2=V
  const bf16* W = Wb + (size_t)which * 1048576;
  const float* bias = (which == 0) ? bq : (which == 1) ? bk : bv;
  const int tNl = tN & 1023;
  const float oscale = (which == 0) ? 0.18033688011112042f : 1.0f;  // 0.125*log2e
  const int wrow = (wave >> 1) * 64, wcol = (wave & 1) * 64;
  const f32x4 fz = {0.f, 0.f, 0.f, 0.f};

  f32x4 acc[4][4];
#pragma unroll
  for (int i = 0; i < 4; ++i)
#pragma unroll
    for (int j = 0; j < 4; ++j) acc[i][j] = fz;

  // staging coords: chunk tid -> row r0, col c0; chunk tid+256 -> row r0+64.
  const int r0 = tid >> 2, c0 = (tid & 3) << 3;

  // prologue: tile 0 into buf 0
  async16(X + (size_t)(tM + r0) * Kd + c0, &sA[0][0] + tid * 8);
  async16(X + (size_t)(tM + r0 + 64) * Kd + c0, &sA[0][0] + (tid + 256) * 8);
  async16(W + (size_t)(tNl + r0) * Kd + c0, &sB[0][0] + tid * 8);
  async16(W + (size_t)(tNl + r0 + 64) * Kd + c0, &sB[0][0] + (tid + 256) * 8);
  __syncthreads();

  for (int k0 = 0; k0 < Kd; k0 += 32) {
    const int cur = (k0 >> 5) & 1;
    if (k0 + 32 < Kd) {  // issue next tile; drains under this iter's compute
      const int kn = k0 + 32;
      bf16* an = &sA[cur ^ 1][0];
      bf16* bn = &sB[cur ^ 1][0];
      async16(X + (size_t)(tM + r0) * Kd + kn + c0, an + tid * 8);
      async16(X + (size_t)(tM + r0 + 64) * Kd + kn + c0, an + (tid + 256) * 8);
      async16(W + (size_t)(tNl + r0) * Kd + kn + c0, bn + tid * 8);
      async16(W + (size_t)(tNl + r0 + 64) * Kd + kn + c0, bn + (tid + 256) * 8);
    }
    bf16x8 aF[4], bF[4];
#pragma unroll
    for (int i = 0; i < 4; ++i)
      aF[i] = *(const bf16x8*)(&sA[cur][0] + (wrow + i * 16 + ln) * 32 + g * 8);
#pragma unroll
    for (int j = 0; j < 4; ++j)
      bF[j] = *(const bf16x8*)(&sB[cur][0] + (wcol + j * 16 + ln) * 32 + g * 8);
#pragma unroll
    for (int i = 0; i < 4; ++i)
#pragma unroll
      for (int j = 0; j < 4; ++j) acc[i][j] = mfma16(aF[i], bF[j], acc[i][j]);
    __syncthreads();  // publishes buf^1 (loads aged through compute), retires reads
  }

  bf16* outw = out + (size_t)which * 4194304;
#pragma unroll
  for (int j = 0; j < 4; ++j) {
    const int nl = tNl + wcol + j * 16 + ln;
    const float bvf = bias[nl];
    const int h = nl >> 6, d = nl & 63;
#pragma unroll
    for (int i = 0; i < 4; ++i) {
#pragma unroll
      for (int r = 0; r < 4; ++r) {
        const int m = tM + wrow + i * 16 + g * 4 + r;
        const int b = m >> 11, s = m & 2047;
        const float v = (acc[i][j][r] + bvf) * oscale;
        outw[(((size_t)(b * 16 + h) * 2048 + s) << 6) + d] = __float2bfloat16(v);
      }
    }
  }
}

// ---- out projection (bf16 x bf16 -> f32). 64x64 tiles, grid (16,64),
// double-buffered staging (1 barrier/iter), LDS 16KB -> still 4 blocks/CU. ----
__global__ __launch_bounds__(256, 4) void out_gemm(
    const bf16* __restrict__ X, const bf16* __restrict__ W,
    const float* __restrict__ bias, float* __restrict__ out) {
  constexpr int Kd = 1024;
  __shared__ bf16 sA[2][64 * 32];
  __shared__ bf16 sB[2][64 * 32];
  const int tid = threadIdx.x;
  const int wave = tid >> 6, lane = tid & 63;
  const int g = lane >> 4, ln = lane & 15;
  const int tM = blockIdx.y * 64, tN = blockIdx.x * 64;
  const f32x4 fz = {0.f, 0.f, 0.f, 0.f};

  f32x4 acc[4];
#pragma unroll
  for (int j = 0; j < 4; ++j) acc[j] = fz;

  const int srow = tid >> 2, scol = (tid & 3) << 3;
  // prologue: tile 0 into buf 0
  async16(X + (size_t)(tM + srow) * Kd + scol, &sA[0][0] + tid * 8);
  async16(W + (size_t)(tN + srow) * Kd + scol, &sB[0][0] + tid * 8);
  __syncthreads();

  for (int k0 = 0; k0 < Kd; k0 += 32) {
    const int cur = (k0 >> 5) & 1;
    if (k0 + 32 < Kd) {
      async16(X + (size_t)(tM + srow) * Kd + k0 + 32 + scol, &sA[cur ^ 1][0] + tid * 8);
      async16(W + (size_t)(tN + srow) * Kd + k0 + 32 + scol, &sB[cur ^ 1][0] + tid * 8);
    }
    const bf16x8 aF = *(const bf16x8*)(&sA[cur][0] + (wave * 16 + ln) * 32 + g * 8);
    bf16x8 bF[4];
#pragma unroll
    for (int j = 0; j < 4; ++j)
      bF[j] = *(const bf16x8*)(&sB[cur][0] + (j * 16 + ln) * 32 + g * 8);
#pragma unroll
    for (int j = 0; j < 4; ++j) acc[j] = mfma16(aF, bF[j], acc[j]);
    __syncthreads();
  }

#pragma unroll
  for (int j = 0; j < 4; ++j) {
    const int n = tN + j * 16 + ln;
    const float bvf = bias[n];
#pragma unroll
    for (int r = 0; r < 4; ++r) {
      const int m = tM + wave * 16 + g * 4 + r;
      out[(size_t)m * 1024 + n] = acc[j][r] + bvf;
    }
  }
}

// ---- flash attention, causal, S^T formulation, fixed-max softmax ----
// Round-10 verified best (43.9us): balanced per-CU quartet mapping.
// Dispatch: XCD = L%8, slot = L/256. Co-resident blocks on one CU differ by
// dL=256 (dpy=8): same head, same q0, quadrants s=0..3. qt = {31-q0, 16+q0,
// 15-q0, q0} partitions [0,32); every CU's quartet sums to 66 iterations —
// flattens the drain tail; same-head quartet adds K/V L1/L2 reuse.
// Grid (32,32), 4 waves/block. Row-sum on the MFMA pipe (ones-B-frag).
// LDS: sK[64][72] (9.2KB) + sVf[64*64] frag-major (8KB).
__global__ __launch_bounds__(256, 4) void attn_kernel(
    const bf16* __restrict__ Q, const bf16* __restrict__ K,
    const bf16* __restrict__ V, bf16* __restrict__ O) {
  constexpr int S = 2048, D = 64;
  __shared__ bf16 sK[64 * 72];
  __shared__ bf16 sVf[64 * 64];

  const int tid = threadIdx.x;
  const int w = tid >> 6, lane = tid & 63;
  const int g = lane >> 4, ln = lane & 15;
  // work remap: (px,py) -> (bh, qt), bijective (balanced quartet).
  const int px = blockIdx.x, py = blockIdx.y;
  const int bh = (px & 7) * 4 + (py & 3);             // XCD-pinned head
  const int s = py >> 3;                              // CU-slot quadrant
  const int q0 = (px >> 3) + 4 * ((py >> 2) & 1);     // [0,8)
  const int qt = (s == 0) ? 31 - q0
               : (s == 1) ? 16 + q0
               : (s == 2) ? 15 - q0
                          : q0;
  const int b = bh >> 4, h = bh & 15;
  const f32x4 fz = {0.f, 0.f, 0.f, 0.f};

  const bf16* Qb = Q + (size_t)bh * S * D;
  const bf16* Kb = K + (size_t)bh * S * D;
  const bf16* Vb = V + (size_t)bh * S * D;

  // K staging coords (2 x b128 per thread)
  const int kr0 = tid >> 3, kc0 = (tid & 7) << 3;
  // V staging: dest chunk c -> 8 elems ((kb*4+db)*64 + vg*16 + l0)*4 + i,
  // sources V[kb*16+vg*4+i][db*16+l0..l0+1] (4 dword loads -> 1 b128 store)
  int vsrc[2][4], vdst[2];
#pragma unroll
  for (int t = 0; t < 2; ++t) {
    const int c = tid + t * 256;
    const int u = c * 2;
    const int kbdb = u >> 6, vg = (u >> 4) & 3, l0 = u & 15;
    const int kb = kbdb >> 2, db = kbdb & 3;
#pragma unroll
    for (int i = 0; i < 4; ++i) vsrc[t][i] = (kb * 16 + vg * 4 + i) * 64 + db * 16 + l0;
    vdst[t] = c * 8;
  }

  // Q B-frags (B[k=d][n=q]: n=ln, k=g*8+j); Q pre-scaled by SCALE*log2e
  bf16x8 qf[2];
#pragma unroll
  for (int kc = 0; kc < 2; ++kc)
    qf[kc] = *(const bf16x8*)(Qb + (size_t)(qt * 64 + w * 16 + ln) * D + kc * 32 + g * 8);

  f32x4 oacc[4];
#pragma unroll
  for (int db = 0; db < 4; ++db) oacc[db] = fz;
  f32x4 lacc = fz;  // row-sum accumulator (MFMA ones trick)
  const short onebf = (short)0x3F80;  // bf16 1.0
  const bf16x4 onesf = {onebf, onebf, onebf, onebf};

  // prologue: prefetch tile 0 into registers
  uint4 kreg0 = *(const uint4*)(Kb + (size_t)kr0 * D + kc0);
  uint4 kreg1 = *(const uint4*)(Kb + (size_t)(kr0 + 32) * D + kc0);
  uint32_t vreg[2][4];
#pragma unroll
  for (int t = 0; t < 2; ++t)
#pragma unroll
    for (int i = 0; i < 4; ++i) vreg[t][i] = *(const uint32_t*)(Vb + vsrc[t][i]);

  for (int kt = 0; kt <= qt; ++kt) {
    __syncthreads();  // prev-iter LDS reads complete
    *(uint4*)(sK + kr0 * 72 + kc0) = kreg0;
    *(uint4*)(sK + (kr0 + 32) * 72 + kc0) = kreg1;
#pragma unroll
    for (int t = 0; t < 2; ++t) {
      const uint32_t d0 = vreg[t][0], d1 = vreg[t][1], d2 = vreg[t][2], d3 = vreg[t][3];
      uint4 pk;
      pk.x = (d1 << 16) | (d0 & 0xffffu);
      pk.y = (d3 << 16) | (d2 & 0xffffu);
      pk.z = (d1 & 0xffff0000u) | (d0 >> 16);
      pk.w = (d3 & 0xffff0000u) | (d2 >> 16);
      *(uint4*)(sVf + vdst[t]) = pk;
    }
    __syncthreads();
    if (kt < qt) {  // prefetch next tile (overlaps compute)
      const size_t nb = (size_t)(kt + 1) * 64;
      kreg0 = *(const uint4*)(Kb + (nb + kr0) * D + kc0);
      kreg1 = *(const uint4*)(Kb + (nb + kr0 + 32) * D + kc0);
#pragma unroll
      for (int t = 0; t < 2; ++t)
#pragma unroll
        for (int i = 0; i < 4; ++i)
          vreg[t][i] = *(const uint32_t*)(Vb + nb * D + vsrc[t][i]);
    }

    // S^T = K.Q^T : A=K (m=key), B=Q (n=q); 4 key-blocks x 2 k-chunks
    f32x4 sacc[4];
#pragma unroll
    for (int kb = 0; kb < 4; ++kb) sacc[kb] = fz;
#pragma unroll
    for (int kb = 0; kb < 4; ++kb) {
      const bf16x8 k0 = *(const bf16x8*)(sK + (kb * 16 + ln) * 72 + g * 8);
      const bf16x8 k1 = *(const bf16x8*)(sK + (kb * 16 + ln) * 72 + 32 + g * 8);
      sacc[kb] = mfma16(k0, qf[0], sacc[kb]);
      sacc[kb] = mfma16(k1, qf[1], sacc[kb]);
    }

    // softmax (fixed-max, log2 domain) + causal zero + pack PV A-frags;
    // row-sum folded into lacc on the MFMA pipe.
    const bool diag = (kt == qt);
    const int qloc = w * 16 + ln;  // q row within q-tile
    bf16x4 pa[4];
#pragma unroll
    for (int kb = 0; kb < 4; ++kb) {
      union { bf16 hh[4]; bf16x4 v; } pu;
#pragma unroll
      for (int r = 0; r < 4; ++r) {
        float pv = exp2f(sacc[kb][r]);
        if (diag && (kb * 16 + g * 4 + r > qloc)) pv = 0.f;
        pu.hh[r] = __float2bfloat16(pv);
      }
      pa[kb] = pu.v;
      lacc = mfma_k16(pa[kb], onesf, lacc);
    }

    // O += P V : 16x16x16, A=pa (m=q,k=s), B=V frag-major (k=s,n=d)
#pragma unroll
    for (int db = 0; db < 4; ++db) {
#pragma unroll
      for (int kb = 0; kb < 4; ++kb) {
        const bf16x4 vf =
            *(const bf16x4*)(sVf + ((kb * 4 + db) * 64 + g * 16 + ln) * 4);
        oacc[db] = mfma_k16(pa[kb], vf, oacc[db]);
      }
    }
  }

  // lacc[r] = rowsum for q-row g*4+r (same rows as oacc) -> direct reciprocal
  float invl[4];
#pragma unroll
  for (int r = 0; r < 4; ++r) invl[r] = 1.0f / lacc[r];

  // write ctx [B,S,H,D]: rows = q (4g+r), cols = d (db*16+ln)
#pragma unroll
  for (int db = 0; db < 4; ++db)
#pragma unroll
    for (int r = 0; r < 4; ++r) {
      const int row = qt * 64 + w * 16 + g * 4 + r;
      const int col = db * 16 + ln;
      O[(((size_t)(b * 2048 + row) * 16 + h) << 6) + col] =
          __float2bfloat16(oacc[db][r] * invl[r]);
    }
}

extern "C" void kernel_launch(void* const* d_in, const int* in_sizes, int n_in,
                              void* d_out, int out_size, void* d_ws, size_t ws_size,
                              hipStream_t stream) {
  const float* hs = (const float*)d_in[0];
  // d_in[1] = attn_mask (f32): exactly causal -> applied analytically, not read.
  const float* Wq = (const float*)d_in[2];
  const float* bq = (const float*)d_in[3];
  const float* Wk = (const float*)d_in[4];
  const float* bk = (const float*)d_in[5];
  const float* Wv = (const float*)d_in[6];
  const float* bv = (const float*)d_in[7];
  const float* Wo = (const float*)d_in[8];
  const float* bo = (const float*)d_in[9];
  float* out = (float*)d_out;

  char* ws = (char*)d_ws;
  bf16* XW = (bf16*)ws;                  // [0,16MB): Xb 4M + W's 4x1M bf16
  bf16* Xb = XW;
  bf16* W3b = XW + 4194304;              // Wq,Wk,Wv bf16
  bf16* Wob = XW + 7340032;              // Wo bf16
  bf16* Qw = (bf16*)(ws + (16u << 20));  // [B,H,S,D] bf16, 8 MB each
  bf16* Kw = (bf16*)(ws + (24u << 20));
  bf16* Vw = (bf16*)(ws + (32u << 20));
  bf16* Cw = (bf16*)ws;                  // ctx overlays Xb (dead by then)

  const dim3 blk(256);
  cvt_kernel<<<4096, blk, 0, stream>>>(hs, Wq, Wk, Wv, Wo, XW);
  qkv_gemm<<<dim3(24, 32), blk, 0, stream>>>(Xb, W3b, bq, bk, bv, Qw);
  attn_kernel<<<dim3(32, 32), blk, 0, stream>>>(Qw, Kw, Vw, Cw);
  out_gemm<<<dim3(16, 64), blk, 0, stream>>>(Cw, Wob, bo, out);
}

// Round 13
// 194.759 us; speedup vs baseline: 1.0745x; 1.0450x over previous
//
#include <hip/hip_runtime.h>
#include <hip/hip_bf16.h>
#include <stdint.h>

// CustomAttention: B=2, S=2048, E=1024, H=16, D=64, causal. I/O f32.
// cvt (f32->bf16 precast), qkv_gemm (bf16, BK=64 via two [128][32] panels,
// Q pre-scaled by SCALE*log2e, V written in FRAG-MAJOR tile layout "Vf"),
// flash-attn (S^T formulation, balanced per-CU quartet; V staged by 2
// contiguous async16/thread into double-buffered sVf — no repack, no vreg),
// out_gemm (64x64 tiles, single-buffered — r10 verified).
//
// Failed-variant ledger (do not retry):
//  - attn KVBLK=128 reg-prefetch: spills (WRITE 8->78MB, 46->69us).
//  - attn 1-barrier LDS dbuf via reg->ds_write: lgkmcnt in-order retire puts
//    the write phase on the read critical path (46.5->52us).
//  - attn setprio on MFMA clusters: 4-wave lockstep = m190 regime, +2.6us.
//  - qkv XCD-rect swizzle: post-timing nondeterministic divergence. Reverted.
//  - attn 128-q/8-wave block: halves independent barrier groups/CU, +5us.
//  - __launch_bounds__(256,8): min-waves arg CAPS total regs (gfx950 unified
//    file) at 64 -> VGPR 32 + 167MB spill, attn 128us.
//  - attn V^T consume + XOR-chunk swizzle: 128B rows = one bank period ->
//    unavoidable 4-way PV conflict (canary 2.16M->15.1M, 43.9->57.6us).
//    Frag-major LDS image is bank-optimal — KEEP IT; move the permutation
//    to the producer (this round) instead of the consumer.
//  - qkv/out global_load_lds dbuf (BK=32, 1 barrier/iter): equal barrier
//    count, half the per-barrier MFMA amortization -> total +6us. Reverted.
//  - SQ_LDS_BANK_CONFLICT==2162688 is the attn structure's REAL constant
//    (moved 7x when the pattern changed) — valid regression canary.

typedef __hip_bfloat16 bf16;
typedef short bf16x8 __attribute__((ext_vector_type(8)));
typedef short bf16x4 __attribute__((ext_vector_type(4)));
typedef float f32x4 __attribute__((ext_vector_type(4)));

__device__ __forceinline__ f32x4 mfma16(bf16x8 a, bf16x8 b, f32x4 c) {
  return __builtin_amdgcn_mfma_f32_16x16x32_bf16(a, b, c, 0, 0, 0);
}

// 16x16x16 bf16 MFMA (K=16): A[m=ln][k=4g+i], B[k=4g+i][n=ln], C/D standard.
__device__ __forceinline__ f32x4 mfma_k16(bf16x4 a, bf16x4 b, f32x4 c) {
#if __has_builtin(__builtin_amdgcn_mfma_f32_16x16x16bf16_1k)
  return __builtin_amdgcn_mfma_f32_16x16x16bf16_1k(a, b, c, 0, 0, 0);
#else
  f32x4 d;
  asm volatile("v_mfma_f32_16x16x16_bf16 %0, %1, %2, %3\n\ts_nop 7\n\ts_nop 7"
               : "=v"(d)
               : "v"(a), "v"(b), "v"(c));
  return d;
#endif
}

__device__ __forceinline__ void async16(const void* g, void* l) {
  __builtin_amdgcn_global_load_lds((const __attribute__((address_space(1))) void*)g,
                                   (__attribute__((address_space(3))) void*)l, 16, 0, 0);
}

// ---- precast: hs (4M) + Wq,Wk,Wv,Wo (1M each) f32 -> one 8M bf16 array ----
__global__ __launch_bounds__(256) void cvt_kernel(
    const float* __restrict__ hs, const float* __restrict__ Wq,
    const float* __restrict__ Wk, const float* __restrict__ Wv,
    const float* __restrict__ Wo, bf16* __restrict__ dst) {
  const size_t e = ((size_t)blockIdx.x * 256 + threadIdx.x) * 8;
  const float* src;
  size_t off;
  if (e < 4194304) {
    src = hs; off = e;
  } else {
    const size_t w = e - 4194304;
    const int wi = (int)(w >> 20);
    src = (wi == 0) ? Wq : (wi == 1) ? Wk : (wi == 2) ? Wv : Wo;
    off = w & 1048575;
  }
  const float4 a = *(const float4*)(src + off);
  const float4 b = *(const float4*)(src + off + 4);
  union { bf16 h[8]; uint4 u; } p;
  p.h[0] = __float2bfloat16(a.x); p.h[1] = __float2bfloat16(a.y);
  p.h[2] = __float2bfloat16(a.z); p.h[3] = __float2bfloat16(a.w);
  p.h[4] = __float2bfloat16(b.x); p.h[5] = __float2bfloat16(b.y);
  p.h[6] = __float2bfloat16(b.z); p.h[7] = __float2bfloat16(b.w);
  *(uint4*)(dst + e) = p.u;
}

// ---- fused QKV GEMM (all bf16). M=4096, N=3072, K=1024. BK=64 as two
// [128][32] panels (r10-verified). V (which==2) is written in FRAG-MAJOR
// tile layout Vf: per [b,h], 32 tiles (64 keys each) of 4096 elems;
// V[ks][d] at tile*(4096) + ((ks>>4)*4 + (d>>4))*256 + ((ks&15&~3|..)):
// precisely pos = (kb*4+db)*256 + (vg*16+l0)*4 + i with kb=ks>>4,
// vg=(ks>>2)&3, i=ks&3, db=d>>4, l0=d&15. For this kernel's C-frag:
// kb=i, vg=g, db=j, l0=ln -> each lane's 4 acc values are CONTIGUOUS
// (one bf16x4 store per frag; wave writes 512B contiguous). ----
__global__ __launch_bounds__(256, 3) void qkv_gemm(
    const bf16* __restrict__ X, const bf16* __restrict__ Wb,
    const float* __restrict__ bq, const float* __restrict__ bk,
    const float* __restrict__ bv, bf16* __restrict__ out) {
  constexpr int Kd = 1024;
  __shared__ bf16 sA[2][128 * 32];
  __shared__ bf16 sB[2][128 * 32];
  const int tid = threadIdx.x;
  const int wave = tid >> 6, lane = tid & 63;
  const int g = lane >> 4, ln = lane & 15;
  const int tM = blockIdx.y * 128, tN = blockIdx.x * 128;
  const int which = tN >> 10;  // 0=Q 1=K 2=V
  const bf16* W = Wb + (size_t)which * 1048576;
  const float* bias = (which == 0) ? bq : (which == 1) ? bk : bv;
  const int tNl = tN & 1023;
  const float oscale = (which == 0) ? 0.18033688011112042f : 1.0f;  // 0.125*log2e
  const int wrow = (wave >> 1) * 64, wcol = (wave & 1) * 64;
  const f32x4 fz = {0.f, 0.f, 0.f, 0.f};

  f32x4 acc[4][4];
#pragma unroll
  for (int i = 0; i < 4; ++i)
#pragma unroll
    for (int j = 0; j < 4; ++j) acc[i][j] = fz;

  // staging decomposition: dest chunk d (16B) -> panel=d>>9, row=(d>>2)&127,
  // cc=d&3; global col = panel*32 + cc*8. Per-wave dests stay linear.
  int srow[4], scol[4];
#pragma unroll
  for (int t = 0; t < 4; ++t) {
    const int d = tid + t * 256;
    srow[t] = (d >> 2) & 127;
    scol[t] = ((d >> 9) << 5) + ((d & 3) << 3);
  }

  for (int k0 = 0; k0 < Kd; k0 += 64) {
    __syncthreads();
#pragma unroll
    for (int t = 0; t < 4; ++t) {
      const int d = tid + t * 256;
      async16(X + (size_t)(tM + srow[t]) * Kd + k0 + scol[t], &sA[0][0] + d * 8);
      async16(W + (size_t)(tNl + srow[t]) * Kd + k0 + scol[t], &sB[0][0] + d * 8);
    }
    __syncthreads();
#pragma unroll
    for (int kk = 0; kk < 2; ++kk) {
      bf16x8 aF[4], bF[4];
#pragma unroll
      for (int i = 0; i < 4; ++i)
        aF[i] = *(const bf16x8*)(&sA[kk][0] + (wrow + i * 16 + ln) * 32 + g * 8);
#pragma unroll
      for (int j = 0; j < 4; ++j)
        bF[j] = *(const bf16x8*)(&sB[kk][0] + (wcol + j * 16 + ln) * 32 + g * 8);
#pragma unroll
      for (int i = 0; i < 4; ++i)
#pragma unroll
        for (int j = 0; j < 4; ++j) acc[i][j] = mfma16(aF[i], bF[j], acc[i][j]);
    }
  }

  bf16* outw = out + (size_t)which * 4194304;
  if (which == 2) {
    // Vf epilogue: kb=i, vg=g, db=j, l0=ln -> bf16x4 store per frag.
    const int hh = (tNl + wcol) >> 6;
#pragma unroll
    for (int j = 0; j < 4; ++j) {
      const int nl = tNl + wcol + j * 16 + ln;
      const float bvf = bias[nl];
#pragma unroll
      for (int i = 0; i < 4; ++i) {
        const int m0 = tM + wrow + i * 16 + g * 4;
        const int b = m0 >> 11, t = (m0 & 2047) >> 6;
        union { bf16 hv[4]; bf16x4 v; } pk;
#pragma unroll
        for (int r = 0; r < 4; ++r) pk.hv[r] = __float2bfloat16(acc[i][j][r] + bvf);
        *(bf16x4*)(outw + (((size_t)(b * 16 + hh) * 32 + t) << 12) +
                   (i * 4 + j) * 256 + (g * 16 + ln) * 4) = pk.v;
      }
    }
  } else {
#pragma unroll
    for (int j = 0; j < 4; ++j) {
      const int nl = tNl + wcol + j * 16 + ln;
      const float bvf = bias[nl];
      const int h = nl >> 6, d = nl & 63;
#pragma unroll
      for (int i = 0; i < 4; ++i) {
#pragma unroll
        for (int r = 0; r < 4; ++r) {
          const int m = tM + wrow + i * 16 + g * 4 + r;
          const int b = m >> 11, s = m & 2047;
          const float v = (acc[i][j][r] + bvf) * oscale;
          outw[(((size_t)(b * 16 + h) * 2048 + s) << 6) + d] = __float2bfloat16(v);
        }
      }
    }
  }
}

// ---- out projection (bf16 x bf16 -> f32). 64x64 tiles, grid (16,64) ----
__global__ __launch_bounds__(256, 4) void out_gemm(
    const bf16* __restrict__ X, const bf16* __restrict__ W,
    const float* __restrict__ bias, float* __restrict__ out) {
  constexpr int Kd = 1024;
  __shared__ bf16 sA[64 * 32];
  __shared__ bf16 sB[64 * 32];
  const int tid = threadIdx.x;
  const int wave = tid >> 6, lane = tid & 63;
  const int g = lane >> 4, ln = lane & 15;
  const int tM = blockIdx.y * 64, tN = blockIdx.x * 64;
  const f32x4 fz = {0.f, 0.f, 0.f, 0.f};

  f32x4 acc[4];
#pragma unroll
  for (int j = 0; j < 4; ++j) acc[j] = fz;

  const int srow = tid >> 2, scol = (tid & 3) << 3;
  for (int k0 = 0; k0 < Kd; k0 += 32) {
    __syncthreads();
    async16(X + (size_t)(tM + srow) * Kd + k0 + scol, sA + tid * 8);
    async16(W + (size_t)(tN + srow) * Kd + k0 + scol, sB + tid * 8);
    __syncthreads();
    const bf16x8 aF = *(const bf16x8*)(sA + (wave * 16 + ln) * 32 + g * 8);
    bf16x8 bF[4];
#pragma unroll
    for (int j = 0; j < 4; ++j)
      bF[j] = *(const bf16x8*)(sB + (j * 16 + ln) * 32 + g * 8);
#pragma unroll
    for (int j = 0; j < 4; ++j) acc[j] = mfma16(aF, bF[j], acc[j]);
  }

#pragma unroll
  for (int j = 0; j < 4; ++j) {
    const int n = tN + j * 16 + ln;
    const float bvf = bias[n];
#pragma unroll
    for (int r = 0; r < 4; ++r) {
      const int m = tM + wave * 16 + g * 4 + r;
      out[(size_t)m * 1024 + n] = acc[j][r] + bvf;
    }
  }
}

// ---- flash attention, causal, S^T formulation, fixed-max softmax ----
// Balanced per-CU quartet mapping (r10/r12 verified best, 43.2us).
// V: staged from the FRAG-MAJOR global buffer Vf by 2 contiguous async16
// per thread into sVf[2][64*64] (double-buffered). Issue for tile kt+1
// happens after barrier B of iter kt (its buffer's last readers retired at
// barrier A of kt); loads age through compute of kt and drain at barrier A
// of kt+1 (vmcnt(0) implicit in __syncthreads). LDS image is bit-identical
// to the verified frag-major layout -> PV reads unchanged (bank canary).
// Removes per iter: 8 scattered V dword loads + ~12 repack VALU + 2
// ds_writes + 8 VGPRs. K path unchanged (reg-staged, 72-pad).
// LDS: sK[64][72] 9.2KB + sVf 16KB = 25.6KB -> 4 blocks/CU.
__global__ __launch_bounds__(256, 4) void attn_kernel(
    const bf16* __restrict__ Q, const bf16* __restrict__ K,
    const bf16* __restrict__ V, bf16* __restrict__ O) {
  constexpr int S = 2048, D = 64;
  __shared__ bf16 sK[64 * 72];
  __shared__ bf16 sVf[2][64 * 64];

  const int tid = threadIdx.x;
  const int w = tid >> 6, lane = tid & 63;
  const int g = lane >> 4, ln = lane & 15;
  // work remap: (px,py) -> (bh, qt), bijective (balanced quartet).
  const int px = blockIdx.x, py = blockIdx.y;
  const int bh = (px & 7) * 4 + (py & 3);             // XCD-pinned head
  const int s = py >> 3;                              // CU-slot quadrant
  const int q0 = (px >> 3) + 4 * ((py >> 2) & 1);     // [0,8)
  const int qt = (s == 0) ? 31 - q0
               : (s == 1) ? 16 + q0
               : (s == 2) ? 15 - q0
                          : q0;
  const int b = bh >> 4, h = bh & 15;
  const f32x4 fz = {0.f, 0.f, 0.f, 0.f};

  const bf16* Qb = Q + (size_t)bh * S * D;
  const bf16* Kb = K + (size_t)bh * S * D;
  const bf16* Vfb = V + (size_t)bh * 131072;  // 32 tiles x 4096 elems

  // K staging coords (2 x b128 per thread)
  const int kr0 = tid >> 3, kc0 = (tid & 7) << 3;

  // Q B-frags (B[k=d][n=q]: n=ln, k=g*8+j); Q pre-scaled by SCALE*log2e
  bf16x8 qf[2];
#pragma unroll
  for (int kc = 0; kc < 2; ++kc)
    qf[kc] = *(const bf16x8*)(Qb + (size_t)(qt * 64 + w * 16 + ln) * D + kc * 32 + g * 8);

  f32x4 oacc[4];
#pragma unroll
  for (int db = 0; db < 4; ++db) oacc[db] = fz;
  f32x4 lacc = fz;  // row-sum accumulator (MFMA ones trick)
  const short onebf = (short)0x3F80;  // bf16 1.0
  const bf16x4 onesf = {onebf, onebf, onebf, onebf};

  // prologue: K tile 0 -> regs; V tile 0 -> sVf[0] via contiguous async16
  uint4 kreg0 = *(const uint4*)(Kb + (size_t)kr0 * D + kc0);
  uint4 kreg1 = *(const uint4*)(Kb + (size_t)(kr0 + 32) * D + kc0);
  async16(Vfb + tid * 8, &sVf[0][0] + tid * 8);
  async16(Vfb + 2048 + tid * 8, &sVf[0][0] + 2048 + tid * 8);

  for (int kt = 0; kt <= qt; ++kt) {
    __syncthreads();  // A: V(kt) loads drained+visible; prev-iter LDS reads retired
    *(uint4*)(sK + kr0 * 72 + kc0) = kreg0;
    *(uint4*)(sK + (kr0 + 32) * 72 + kc0) = kreg1;
    __syncthreads();  // B: sK visible
    if (kt < qt) {
      // issue V tile kt+1 (buffer's readers retired at barrier A above)
      const bf16* vs = Vfb + (kt + 1) * 4096;
      bf16* vb = &sVf[(kt + 1) & 1][0];
      async16(vs + tid * 8, vb + tid * 8);
      async16(vs + 2048 + tid * 8, vb + 2048 + tid * 8);
      const size_t nb = (size_t)(kt + 1) * 64;
      kreg0 = *(const uint4*)(Kb + (nb + kr0) * D + kc0);
      kreg1 = *(const uint4*)(Kb + (nb + kr0 + 32) * D + kc0);
    }

    // S^T = K.Q^T : A=K (m=key), B=Q (n=q); 4 key-blocks x 2 k-chunks
    f32x4 sacc[4];
#pragma unroll
    for (int kb = 0; kb < 4; ++kb) sacc[kb] = fz;
#pragma unroll
    for (int kb = 0; kb < 4; ++kb) {
      const bf16x8 k0 = *(const bf16x8*)(sK + (kb * 16 + ln) * 72 + g * 8);
      const bf16x8 k1 = *(const bf16x8*)(sK + (kb * 16 + ln) * 72 + 32 + g * 8);
      sacc[kb] = mfma16(k0, qf[0], sacc[kb]);
      sacc[kb] = mfma16(k1, qf[1], sacc[kb]);
    }

    // softmax (fixed-max, log2 domain) + causal zero + pack PV A-frags;
    // row-sum folded into lacc on the MFMA pipe.
    const bool diag = (kt == qt);
    const int qloc = w * 16 + ln;  // q row within q-tile
    bf16x4 pa[4];
#pragma unroll
    for (int kb = 0; kb < 4; ++kb) {
      union { bf16 hh[4]; bf16x4 v; } pu;
#pragma unroll
      for (int r = 0; r < 4; ++r) {
        float pv = exp2f(sacc[kb][r]);
        if (diag && (kb * 16 + g * 4 + r > qloc)) pv = 0.f;
        pu.hh[r] = __float2bfloat16(pv);
      }
      pa[kb] = pu.v;
      lacc = mfma_k16(pa[kb], onesf, lacc);
    }

    // O += P V : 16x16x16, A=pa (m=q,k=s), B=V frag-major (k=s,n=d)
    const bf16* sVc = &sVf[kt & 1][0];
#pragma unroll
    for (int db = 0; db < 4; ++db) {
#pragma unroll
      for (int kb = 0; kb < 4; ++kb) {
        const bf16x4 vf =
            *(const bf16x4*)(sVc + ((kb * 4 + db) * 64 + g * 16 + ln) * 4);
        oacc[db] = mfma_k16(pa[kb], vf, oacc[db]);
      }
    }
  }

  // lacc[r] = rowsum for q-row g*4+r (same rows as oacc) -> direct reciprocal
  float invl[4];
#pragma unroll
  for (int r = 0; r < 4; ++r) invl[r] = 1.0f / lacc[r];

  // write ctx [B,S,H,D]: rows = q (4g+r), cols = d (db*16+ln)
#pragma unroll
  for (int db = 0; db < 4; ++db)
#pragma unroll
    for (int r = 0; r < 4; ++r) {
      const int row = qt * 64 + w * 16 + g * 4 + r;
      const int col = db * 16 + ln;
      O[(((size_t)(b * 2048 + row) * 16 + h) << 6) + col] =
          __float2bfloat16(oacc[db][r] * invl[r]);
    }
}

extern "C" void kernel_launch(void* const* d_in, const int* in_sizes, int n_in,
                              void* d_out, int out_size, void* d_ws, size_t ws_size,
                              hipStream_t stream) {
  const float* hs = (const float*)d_in[0];
  // d_in[1] = attn_mask (f32): exactly causal -> applied analytically, not read.
  const float* Wq = (const float*)d_in[2];
  const float* bq = (const float*)d_in[3];
  const float* Wk = (const float*)d_in[4];
  const float* bk = (const float*)d_in[5];
  const float* Wv = (const float*)d_in[6];
  const float* bv = (const float*)d_in[7];
  const float* Wo = (const float*)d_in[8];
  const float* bo = (const float*)d_in[9];
  float* out = (float*)d_out;

  char* ws = (char*)d_ws;
  bf16* XW = (bf16*)ws;                  // [0,16MB): Xb 4M + W's 4x1M bf16
  bf16* Xb = XW;
  bf16* W3b = XW + 4194304;              // Wq,Wk,Wv bf16
  bf16* Wob = XW + 7340032;              // Wo bf16
  bf16* Qw = (bf16*)(ws + (16u << 20));  // [B,H,S,D] bf16, 8 MB each
  bf16* Kw = (bf16*)(ws + (24u << 20));
  bf16* Vw = (bf16*)(ws + (32u << 20));  // Vf: frag-major tiles, 8 MB
  bf16* Cw = (bf16*)ws;                  // ctx overlays Xb (dead by then)

  const dim3 blk(256);
  cvt_kernel<<<4096, blk, 0, stream>>>(hs, Wq, Wk, Wv, Wo, XW);
  qkv_gemm<<<dim3(24, 32), blk, 0, stream>>>(Xb, W3b, bq, bk, bv, Qw);
  attn_kernel<<<dim3(32, 32), blk, 0, stream>>>(Qw, Kw, Vw, Cw);
  out_gemm<<<dim3(16, 64), blk, 0, stream>>>(Cw, Wob, bo, out);
}